// Round 4
// baseline (443.998 us; speedup 1.0000x reference)
//
#include <hip/hip_runtime.h>

#define STEPS   200
#define NT      199
#define BATCH   512
#define IN_DIM  784
#define OUT_DIM 10
#define NCHUNK  8
#define CHUNK   98                 // IN_DIM / NCHUNK
#define WSTR    12                 // weight LDS row stride (48 B, 16 B aligned)

// One block per batch element; 1024 threads = 8 input-chunks x 128 t-pair lanes.
// LDS is a UNION: phase 1 uses it as weights [784][12] (37.6 KB); after a
// barrier it becomes drive partials [8][199][10] (63.7 KB). 63.7 KB -> 2
// blocks/CU, 32 waves/CU. VGPR ~56 -> 8 waves/SIMD.
__global__ __launch_bounds__(1024, 8) void snn_fwd(
    const float* __restrict__ x,    // [BATCH, IN_DIM, STEPS]
    const float* __restrict__ w,    // [OUT_DIM, IN_DIM]
    float* __restrict__ out)        // [BATCH, OUT_DIM]
{
    __shared__ float smem[NCHUNK * NT * OUT_DIM];   // 15920 floats = 63.7 KB
    float* w_lds = smem;                            // [IN_DIM][WSTR]   phase 1
    float* dlds  = smem;                            // [NCHUNK][NT][10] phase 2

    const int b   = blockIdx.x;
    const int tid = threadIdx.x;
    const int c   = tid >> 7;       // input chunk 0..7
    const int tp  = tid & 127;      // t-pair lane
    const int t0  = tp * 2;         // this lane's two time bins: t0, t0+1

    // Stage weights transposed: w_lds[i*WSTR+o] = w[o*IN+i] (coalesced reads).
    for (int idx = tid; idx < IN_DIM * OUT_DIM; idx += 1024) {
        int o = idx / IN_DIM;
        int i = idx - o * IN_DIM;
        w_lds[i * WSTR + o] = w[idx];
    }
    __syncthreads();

    float accA[OUT_DIM], accB[OUT_DIM];
    #pragma unroll
    for (int o = 0; o < OUT_DIM; ++o) { accA[o] = 0.0f; accB[o] = 0.0f; }

    if (t0 < NT) {
        const float* xb = x + (size_t)b * IN_DIM * STEPS + t0;
        const int i0 = c * CHUNK;

        // Spikes are exactly 1.0; skipping +0.0 adds is bit-identical to the
        // dense in-order accumulation, so sparsity costs no exactness.
        #define CONSUME1(xv, ii)                                                 \
            do {                                                                 \
                if ((xv).x != 0.0f || (xv).y != 0.0f) {                          \
                    const float4 w0 = *(const float4*)&w_lds[(ii) * WSTR + 0];   \
                    const float4 w1 = *(const float4*)&w_lds[(ii) * WSTR + 4];   \
                    const float2 w2 = *(const float2*)&w_lds[(ii) * WSTR + 8];   \
                    if ((xv).x != 0.0f) {                                        \
                        accA[0] += w0.x; accA[1] += w0.y; accA[2] += w0.z;       \
                        accA[3] += w0.w; accA[4] += w1.x; accA[5] += w1.y;       \
                        accA[6] += w1.z; accA[7] += w1.w; accA[8] += w2.x;       \
                        accA[9] += w2.y;                                         \
                    }                                                            \
                    if ((xv).y != 0.0f) {                                        \
                        accB[0] += w0.x; accB[1] += w0.y; accB[2] += w0.z;       \
                        accB[3] += w0.w; accB[4] += w1.x; accB[5] += w1.y;       \
                        accB[6] += w1.z; accB[7] += w1.w; accB[8] += w2.x;       \
                        accB[9] += w2.y;                                         \
                    }                                                            \
                }                                                                \
            } while (0)

        #define LOADG(buf, gbase)                                                \
            do {                                                                 \
                _Pragma("unroll")                                                \
                for (int k = 0; k < 4; ++k)                                      \
                    (buf)[k] = *(const float2*)(xb + (size_t)((gbase) + k) * STEPS); \
            } while (0)

        #define CONS4(buf, gbase)                                                \
            do {                                                                 \
                _Pragma("unroll")                                                \
                for (int k = 0; k < 4; ++k) CONSUME1((buf)[k], (gbase) + k);     \
            } while (0)

        // 98 inputs = 24 groups of 4 + tail of 2. Ping-pong A/B so consuming
        // one buffer always overlaps the other buffer's loads (vmcnt(4), not 0).
        float2 A[4], B[4];
        LOADG(A, i0);                         // group 0
        for (int g = 0; g < 22; g += 2) {
            LOADG(B, i0 + (g + 1) * 4);
            CONS4(A, i0 + g * 4);
            LOADG(A, i0 + (g + 2) * 4);
            CONS4(B, i0 + (g + 1) * 4);
        }
        LOADG(B, i0 + 92);                    // group 23
        CONS4(A, i0 + 88);                    // group 22
        A[0] = *(const float2*)(xb + (size_t)(i0 + 96) * STEPS);
        A[1] = *(const float2*)(xb + (size_t)(i0 + 97) * STEPS);
        CONS4(B, i0 + 92);                    // group 23
        CONSUME1(A[0], i0 + 96);              // tail
        CONSUME1(A[1], i0 + 97);

        #undef CONSUME1
        #undef LOADG
        #undef CONS4
    }

    __syncthreads();   // weights dead; smem becomes drive partials

    if (t0 < NT) {
        #pragma unroll
        for (int o = 0; o < OUT_DIM; ++o)
            dlds[(c * NT + t0) * OUT_DIM + o] = accA[o];
        if (t0 + 1 < NT) {
            #pragma unroll
            for (int o = 0; o < OUT_DIM; ++o)
                dlds[(c * NT + t0 + 1) * OUT_DIM + o] = accB[o];
        }
    }
    __syncthreads();

    // LIF scan + first-spike time: one thread per output neuron.
    // Fixed ascending-chunk merge keeps fp summation deterministic.
    if (tid < OUT_DIM) {
        const int o = tid;
        const float a_m = 0.995f;   // 1 - DT/TAU_M
        const float b_m = 0.005f;   // DT/TAU_M
        const float a_s = 0.98f;    // 1 - DT/TAU_S

        float V = 0.0f, I = 0.0f;
        int fst = 0;
        for (int s = 0; s < NT; ++s) {
            float drv = 0.0f;
            #pragma unroll
            for (int c8 = 0; c8 < NCHUNK; ++c8)
                drv += dlds[(c8 * NT + s) * OUT_DIM + o];
            float Vn = a_m * V + b_m * I;   // old I, per reference ordering
            I = a_s * I + drv;
            if (Vn > 1.0f) {
                if (fst == 0) fst = s + 1;  // +1: output zero-padded at t=0
                V = 0.0f;
            } else {
                V = Vn;
            }
        }
        out[b * OUT_DIM + o] = (fst == 0) ? (float)(STEPS - 1) : (float)fst;
    }
}

extern "C" void kernel_launch(void* const* d_in, const int* in_sizes, int n_in,
                              void* d_out, int out_size, void* d_ws, size_t ws_size,
                              hipStream_t stream) {
    const float* x = (const float*)d_in[0];   // [512, 784, 200] fp32
    const float* w = (const float*)d_in[1];   // [10, 784] fp32
    float* out = (float*)d_out;               // [512, 10] fp32
    snn_fwd<<<dim3(BATCH), dim3(1024), 0, stream>>>(x, w, out);
}